// Round 2
// baseline (97.156 us; speedup 1.0000x reference)
//
#include <hip/hip_runtime.h>
#include <math.h>
#include <stdint.h>

#define NV 512
#define NF 1024
#define TRI_STRIDE 16
#define TRI_CHUNK 64
#define NCHUNK (NF / TRI_CHUNK)

// ws layout:
//   keys   : u64 [16384]        @ 0        (131072 B)
//   vdata  : f64 [4][512]       @ 131072   (16384 B)   xs, ys, z_ndc, inv_w
//   tridata: f64 [1024*16]      @ 147456   (131072 B)
// total 278528 B

__global__ __launch_bounds__(1024) void setup_kernel(
    const float* __restrict__ v, const int* __restrict__ fidx,
    const float* __restrict__ camf, const float* __restrict__ camc,
    const float* __restrict__ camt, const float* __restrict__ camrt,
    double* __restrict__ vdata, double* __restrict__ tridata,
    unsigned long long* __restrict__ keys)
{
#pragma clang fp contract(off)
  __shared__ double sM[16];
  __shared__ double sxs[NV], sys_[NV], szn[NV];
  __shared__ int svld[NV];
  const int tid = threadIdx.x;

  for (int i = tid; i < 16384; i += 1024) keys[i] = ~0ull;

  if (tid == 0) {
    // ---- Rodrigues: scalar part in f32 (numpy NEP50 weak promotion),
    //      matrix part in f64 (np.eye/np.zeros are float64) ----
    float r0f = camrt[0], r1f = camrt[1], r2f = camrt[2];
    float th = sqrtf(((r0f * r0f + r1f * r1f) + r2f * r2f) + 1e-12f);
    float k0 = r0f / th, k1 = r1f / th, k2 = r2f / th;
    float sthf = sinf(th);
    float cthf = 1.0f - cosf(th);
    double K[3][3] = {{0.0, -(double)k2, (double)k1},
                      {(double)k2, 0.0, -(double)k0},
                      {-(double)k1, (double)k0, 0.0}};
    double KK[3][3];
    for (int i = 0; i < 3; ++i)
      for (int j = 0; j < 3; ++j)
        KK[i][j] = (K[i][0] * K[0][j] + K[i][1] * K[1][j]) + K[i][2] * K[2][j];
    double R[3][3];
    for (int i = 0; i < 3; ++i)
      for (int j = 0; j < 3; ++j) {
        double e = (i == j) ? 1.0 : 0.0;
        R[i][j] = (e + (double)sthf * K[i][j]) + (double)cthf * KK[i][j];
      }
    // ---- view = Mr @ Mt (f64) ----
    double Mr[4][4], Mt[4][4];
    for (int i = 0; i < 4; ++i)
      for (int j = 0; j < 4; ++j) {
        Mr[i][j] = (i == j) ? 1.0 : 0.0;
        Mt[i][j] = (i == j) ? 1.0 : 0.0;
      }
    for (int i = 0; i < 3; ++i)
      for (int j = 0; j < 3; ++j) Mr[i][j] = R[j][i];
    Mt[3][0] = (double)camt[0]; Mt[3][1] = (double)camt[1]; Mt[3][2] = (double)camt[2];
    double view[4][4];
    for (int i = 0; i < 4; ++i)
      for (int j = 0; j < 4; ++j)
        view[i][j] = ((Mr[i][0] * Mt[0][j] + Mr[i][1] * Mt[1][j]) +
                      Mr[i][2] * Mt[2][j]) + Mr[i][3] * Mt[3][j];
    // ---- perspective: rows 0/1 entries are f32-computed scalars (weak
    //      promotion), row 2 is full-f64 (np.full of python float) ----
    float fcam = 0.5f * (camf[0] + camf[1]);
    float nf = 0.1f / fcam;
    float ccx = camc[0], ccy = camc[1];
    float right = (128.0f - (ccx + 0.5f)) * nf;
    float left = -(ccx + 0.5f) * nf;
    float top = (ccy + 0.5f) * nf;
    float bottom = -((128.0f - ccy) + 0.5f) * nf;
    float m00f = 0.2f / (right - left);
    float m02f = (right + left) / (right - left);
    float m11f = 0.2f / (top - bottom);
    float m12f = (top + bottom) / (top - bottom);
    double P[4][4] = {
        {(double)m00f, 0.0, (double)m02f, 0.0},
        {0.0, (double)m11f, (double)m12f, 0.0},
        {0.0, 0.0, -(10.0 + 0.1) / (10.0 - 0.1),
         -2.0 * 10.0 * 0.1 / (10.0 - 0.1)},
        {0.0, 0.0, -1.0, 0.0}};
    // M = view @ m.T   (mT[k][j] = P[j][k])
    for (int i = 0; i < 4; ++i)
      for (int j = 0; j < 4; ++j)
        sM[i * 4 + j] = ((view[i][0] * P[j][0] + view[i][1] * P[j][1]) +
                         view[i][2] * P[j][2]) + view[i][3] * P[j][3];
  }
  __syncthreads();

  // ---- vertex transform (f64) ----
  if (tid < NV) {
    double x = (double)v[tid * 3 + 0];
    double y = (double)v[tid * 3 + 1];
    double zz = (double)v[tid * 3 + 2];
    double c0 = ((x * sM[0] + y * sM[4]) + zz * sM[8]) + sM[12];
    double c1 = ((x * sM[1] + y * sM[5]) + zz * sM[9]) + sM[13];
    double c2 = ((x * sM[2] + y * sM[6]) + zz * sM[10]) + sM[14];
    double c3 = ((x * sM[3] + y * sM[7]) + zz * sM[11]) + sM[15];
    int valid = c3 > 1e-8;
    double wsafe = valid ? c3 : 1.0;
    double n0 = c0 / wsafe, n1 = c1 / wsafe, n2 = c2 / wsafe;
    double xs = (n0 * 0.5 + 0.5) * 128.0;
    double ys = (0.5 - n1 * 0.5) * 128.0;
    double iw = 1.0 / wsafe;
    sxs[tid] = xs; sys_[tid] = ys; szn[tid] = n2; svld[tid] = valid;
    vdata[0 * NV + tid] = xs;
    vdata[1 * NV + tid] = ys;
    vdata[2 * NV + tid] = n2;
    vdata[3 * NV + tid] = iw;
  }
  __syncthreads();

  // ---- triangle setup (f64), one tri per thread ----
  {
    int i0 = fidx[tid * 3 + 0], i1 = fidx[tid * 3 + 1], i2 = fidx[tid * 3 + 2];
    double ax = sxs[i0], ay = sys_[i0];
    double bx = sxs[i1], by = sys_[i1];
    double cx = sxs[i2], cy = sys_[i2];
    double p1 = (bx - ax) * (cy - ay);
    double p2 = (by - ay) * (cx - ax);
    double area = p1 - p2;
    bool ok = (fabs(area) > 1e-8) && svld[i0] && svld[i1] && svld[i2];
    double s = (area > 0.0) ? 1.0 : -1.0;
    double inv_abs = ok ? s / area : 1.0;   // 1/|area|, positive
    double bad = ok ? 0.0 : __builtin_nan("");  // NaN-poison edges of dead tris
    double* td = tridata + tid * TRI_STRIDE;
    td[0] = bx;  td[1] = by;  td[2] = cx;  td[3] = cy;  td[4] = ax;  td[5] = ay;
    td[6] = s * (cx - bx) + bad;  td[7] = s * (cy - by) + bad;
    td[8] = s * (ax - cx) + bad;  td[9] = s * (ay - cy) + bad;
    td[10] = s * (bx - ax) + bad; td[11] = s * (by - ay) + bad;
    td[12] = szn[i0] * inv_abs;
    td[13] = szn[i1] * inv_abs;
    td[14] = szn[i2] * inv_abs;
    td[15] = inv_abs;
  }
}

__global__ __launch_bounds__(256) void raster_kernel(
    const double* __restrict__ tridata, unsigned long long* __restrict__ keys)
{
  __shared__ double st[15][TRI_CHUNK];
  const int tid = threadIdx.x;
  const int chunk = blockIdx.y;
  for (int i = tid; i < 15 * TRI_CHUNK; i += 256) {
    int fld = i >> 6, t = i & 63;
    st[fld][t] = tridata[(chunk * TRI_CHUNK + t) * TRI_STRIDE + fld];
  }
  __syncthreads();

  const int tile = blockIdx.x;
  const int x = ((tile & 7) << 4) + (tid & 15);
  const int y = ((tile >> 3) << 4) + (tid >> 4);
  const double px = (double)x + 0.5, py = (double)y + 0.5;

  double bestz = INFINITY;
  unsigned int bestt = 0;
  for (int t = 0; t < TRI_CHUNK; ++t) {
    // sign-folded edge functions: w = s*E (bit-exact vs s*fl(E))
    double w0 = st[6][t] * (py - st[1][t]) - st[7][t] * (px - st[0][t]);
    double w1 = st[8][t] * (py - st[3][t]) - st[9][t] * (px - st[2][t]);
    double w2 = st[10][t] * (py - st[5][t]) - st[11][t] * (px - st[4][t]);
    double z = (w0 * st[12][t] + w1 * st[13][t]) + w2 * st[14][t];
    bool ins = (w0 >= 0.0) & (w1 >= 0.0) & (w2 >= 0.0) &
               (z >= -1.0) & (z <= 1.0) & (z < bestz);
    if (ins) { bestz = z; bestt = (unsigned int)t; }
  }
  if (bestz < INFINITY) {
    // 54-bit monotone depth key + 10-bit tri index: lexicographic min ==
    // (min depth, first index) to within 2^-52 depth quantization
    unsigned long long zq = (unsigned long long)((bestz + 1.0) * 4503599627370496.0);
    unsigned long long key = (zq << 10) | (unsigned long long)(chunk * TRI_CHUNK + bestt);
    atomicMin(&keys[y * 128 + x], key);
  }
}

__global__ __launch_bounds__(256) void color_kernel(
    const unsigned long long* __restrict__ keys,
    const double* __restrict__ vdata, const double* __restrict__ tridata,
    const int* __restrict__ fidx, const float* __restrict__ vc,
    const float* __restrict__ bg, float* __restrict__ out)
{
  const int p = blockIdx.x * 256 + threadIdx.x;
  if (p >= 16384) return;
  const int x = p & 127, y = p >> 7;
  unsigned long long key = keys[p];
  float cr, cg, cb;
  if (key == ~0ull) {
    cr = bg[0]; cg = bg[1]; cb = bg[2];
  } else {
    unsigned int t = (unsigned int)(key & 1023ull);
    const double* td = tridata + t * TRI_STRIDE;
    double px = (double)x + 0.5, py = (double)y + 0.5;
    double w0 = td[6] * (py - td[1]) - td[7] * (px - td[0]);
    double w1 = td[8] * (py - td[3]) - td[9] * (px - td[2]);
    double w2 = td[10] * (py - td[5]) - td[11] * (px - td[4]);
    double inv = td[15];
    double b0 = w0 * inv, b1 = w1 * inv, b2 = w2 * inv;  // == w/area (sign folds)
    int i0 = fidx[t * 3 + 0], i1 = fidx[t * 3 + 1], i2 = fidx[t * 3 + 2];
    double t0 = b0 * vdata[3 * NV + i0];
    double t1 = b1 * vdata[3 * NV + i1];
    double t2 = b2 * vdata[3 * NV + i2];
    double den = (t0 + t1) + t2;
    if (!(fabs(den) > 1e-8)) den = 1.0;
    cr = (float)((((t0 * (double)vc[i0 * 3 + 0] + t1 * (double)vc[i1 * 3 + 0]) +
                   t2 * (double)vc[i2 * 3 + 0])) / den);
    cg = (float)((((t0 * (double)vc[i0 * 3 + 1] + t1 * (double)vc[i1 * 3 + 1]) +
                   t2 * (double)vc[i2 * 3 + 1])) / den);
    cb = (float)((((t0 * (double)vc[i0 * 3 + 2] + t1 * (double)vc[i1 * 3 + 2]) +
                   t2 * (double)vc[i2 * 3 + 2])) / den);
  }
  out[p * 3 + 0] = cr;
  out[p * 3 + 1] = cg;
  out[p * 3 + 2] = cb;
}

extern "C" void kernel_launch(void* const* d_in, const int* in_sizes, int n_in,
                              void* d_out, int out_size, void* d_ws, size_t ws_size,
                              hipStream_t stream) {
  const float* v = (const float*)d_in[0];
  const float* vc = (const float*)d_in[1];
  const int* fidx = (const int*)d_in[2];
  const float* bg = (const float*)d_in[3];
  const float* camf = (const float*)d_in[4];
  const float* camc = (const float*)d_in[5];
  const float* camt = (const float*)d_in[6];
  const float* camrt = (const float*)d_in[7];
  float* out = (float*)d_out;

  char* ws = (char*)d_ws;
  unsigned long long* keys = (unsigned long long*)ws;       // 131072 B
  double* vdata = (double*)(ws + 131072);                   // 16384 B
  double* tridata = (double*)(ws + 147456);                 // 131072 B

  setup_kernel<<<1, 1024, 0, stream>>>(v, fidx, camf, camc, camt, camrt,
                                       vdata, tridata, keys);
  raster_kernel<<<dim3(64, NCHUNK), 256, 0, stream>>>(tridata, keys);
  color_kernel<<<64, 256, 0, stream>>>(keys, vdata, tridata, fidx, vc, bg, out);
}